// Round 1
// baseline (351.520 us; speedup 1.0000x reference)
//
#include <hip/hip_runtime.h>
#include <stdint.h>

#define EPSF 1e-5f
#define LOG2E 1.4426950408889634f

__device__ __forceinline__ float bflo(uint32_t u){ union{uint32_t u;float f;}c; c.u=u<<16; return c.f; }
__device__ __forceinline__ float bfhi(uint32_t u){ union{uint32_t u;float f;}c; c.u=u&0xffff0000u; return c.f; }
__device__ __forceinline__ uint32_t f2bf(float f){ union{float f;uint32_t u;}c; c.f=f; uint32_t u=c.u; return (u + 0x7fffu + ((u>>16)&1u)) >> 16; }
__device__ __forceinline__ uint32_t pk2(float a, float b){ return f2bf(a) | (f2bf(b)<<16); }

// ---------------- rel_enc packing ----------------
// rqk[j] = {qe0,qe1 | qe2,qe3 | keR0,keR1 | keR2,keR3}  (keR[j] = ke[NJ-1-j])
// rve[j] = {ve0..ve7} packed bf16
__global__ void k_relpack(const float* __restrict__ rel, uint4* __restrict__ rqk,
                          uint4* __restrict__ rve, int NJ) {
  int j = threadIdx.x;
  if (j >= NJ) return;
  const float* q = rel;
  const float* k = rel + 4*NJ;
  const float* v = rel + 8*NJ;
  int jr = NJ-1-j;
  uint4 a;
  a.x = pk2(q[0*NJ+j], q[1*NJ+j]);
  a.y = pk2(q[2*NJ+j], q[3*NJ+j]);
  a.z = pk2(k[0*NJ+jr], k[1*NJ+jr]);
  a.w = pk2(k[2*NJ+jr], k[3*NJ+jr]);
  rqk[j] = a;
  uint4 b;
  b.x = pk2(v[0*NJ+j], v[1*NJ+j]);
  b.y = pk2(v[2*NJ+j], v[3*NJ+j]);
  b.z = pk2(v[4*NJ+j], v[5*NJ+j]);
  b.w = pk2(v[6*NJ+j], v[7*NJ+j]);
  rve[j] = b;
}

// ---------------- 1x1 conv + bn (+residual/relu) ----------------
// IN_NHWC=false: input NCHW [c][p]; true: [p][c]. RESID=false: out NHWC + relu.
// RESID=true: out NCHW, out = relu(val + resid).
template<bool IN_NHWC, bool RESID>
__global__ __launch_bounds__(256)
void k_conv(const float* __restrict__ in, const float* __restrict__ w,
            const float* __restrict__ bn, const float* __restrict__ resid,
            float* __restrict__ out) {
  int p = blockIdx.x * 256 + threadIdx.x;   // spatial pos, 32768 total
  int ob = blockIdx.y * 16;                 // output-channel chunk
  float xv[64];
  if (IN_NHWC) {
    const float4* src = (const float4*)(in + (size_t)p*64);
    #pragma unroll
    for (int c4 = 0; c4 < 16; ++c4) {
      float4 t = src[c4];
      xv[4*c4+0]=t.x; xv[4*c4+1]=t.y; xv[4*c4+2]=t.z; xv[4*c4+3]=t.w;
    }
  } else {
    #pragma unroll
    for (int c = 0; c < 64; ++c) xv[c] = in[c*32768 + p];
  }
  #pragma unroll
  for (int r = 0; r < 16; ++r) {
    int o = ob + r;
    const float* wr = w + o*64;             // uniform -> s_load
    float acc = 0.f;
    #pragma unroll
    for (int c = 0; c < 64; ++c) acc = fmaf(wr[c], xv[c], acc);
    float s = bn[o] * rsqrtf(bn[192+o] + EPSF);       // g/sqrt(v+eps)
    float val = fmaf(acc, s, fmaf(-bn[128+o], s, bn[64+o]));  // acc*s + (b - m*s)
    if (RESID) {
      val = fmaxf(val + resid[o*32768 + p], 0.f);
      out[o*32768 + p] = val;
    } else {
      out[(size_t)p*64 + o] = fmaxf(val, 0.f);
    }
  }
}

// ---------------- kqv projection + bn, packed outputs ----------------
// input NHWC-ish: addr = (y*RS + n*CS)*64.  per (n,head,y): 16 channels:
// k(0..3)->kvK bf16x4, q(4..7)->qb fp32x4, v(8..15)->kvV bf16x8
template<int LEN, int RS, int CS>
__global__ __launch_bounds__(256)
void k_kqv(const float* __restrict__ in, const float* __restrict__ w,
           const float* __restrict__ bn, uint4* __restrict__ kvV,
           uint2* __restrict__ kvK, float* __restrict__ qb) {
  int n = blockIdx.x;
  int head = __builtin_amdgcn_readfirstlane(blockIdx.y*4 + (threadIdx.x>>6));
  int lane = threadIdx.x & 63;
  int y = blockIdx.z*64 + lane;
  const float* src = in + ((size_t)y*RS + (size_t)n*CS)*64;
  float xv[64];
  #pragma unroll
  for (int c4 = 0; c4 < 16; ++c4) {
    float4 t = ((const float4*)src)[c4];
    xv[4*c4+0]=t.x; xv[4*c4+1]=t.y; xv[4*c4+2]=t.z; xv[4*c4+3]=t.w;
  }
  float val[16];
  #pragma unroll
  for (int r = 0; r < 16; ++r) {
    int o = head*16 + r;
    const float* wr = w + o*64;             // uniform -> s_load
    float acc = 0.f;
    #pragma unroll
    for (int c = 0; c < 64; ++c) acc = fmaf(wr[c], xv[c], acc);
    float s = bn[o] * rsqrtf(bn[384+o] + EPSF);
    val[r] = fmaf(acc, s, fmaf(-bn[256+o], s, bn[128+o]));
  }
  size_t base = ((size_t)n*8 + head)*LEN + y;
  uint4 vv; vv.x = pk2(val[8],val[9]);  vv.y = pk2(val[10],val[11]);
            vv.z = pk2(val[12],val[13]); vv.w = pk2(val[14],val[15]);
  kvV[base] = vv;
  uint2 kk; kk.x = pk2(val[0],val[1]); kk.y = pk2(val[2],val[3]);
  kvK[base] = kk;
  float4 qq; qq.x = val[4]; qq.y = val[5]; qq.z = val[6]; qq.w = val[7];
  *(float4*)(qb + base*4) = qq;
}

// ---------------- axial attention core ----------------
// block = (n, head); thread owns XPT query positions x = t + i*NT.
// logits(x,y) = A0*qk + A1*qr + A2*kr + Bc   (pre-scaled by log2e)
// online softmax (exp2 domain); out[(x*XS + n*NS)*64 + hd*8 + d]
template<int LEN, int XPT, bool RELUO, int XS, int NS>
__global__ __launch_bounds__(LEN/XPT)
void k_attn(const uint4* __restrict__ kvV, const uint2* __restrict__ kvK,
            const float* __restrict__ qb, const uint4* __restrict__ rqk,
            const uint4* __restrict__ rve, const float* __restrict__ lbn,
            float* __restrict__ out) {
  constexpr int NJ = 2*LEN-1;
  constexpr int NT = LEN/XPT;
  int n  = blockIdx.x >> 3;
  int hd = blockIdx.x & 7;
  int t  = threadIdx.x;
  __shared__ uint4 sV[LEN];
  __shared__ uint2 sK[LEN];
  __shared__ uint4 sQK[NJ];
  __shared__ uint4 sVE[NJ];
  size_t kvbase = ((size_t)n*8 + hd)*LEN;
  for (int i = t; i < LEN; i += NT) { sV[i] = kvV[kvbase+i]; sK[i] = kvK[kvbase+i]; }
  for (int i = t; i < NJ;  i += NT) { sQK[i] = rqk[i]; sVE[i] = rve[i]; }
  // logits-bn constants (uniform scalar loads)
  float A0,A1,A2,Bc;
  {
    int c0 = hd, c1 = 8+hd, c2 = 16+hd;
    float s0 = lbn[c0]*rsqrtf(lbn[72+c0]+EPSF);
    float s1 = lbn[c1]*rsqrtf(lbn[72+c1]+EPSF);
    float s2 = lbn[c2]*rsqrtf(lbn[72+c2]+EPSF);
    float t0 = fmaf(-lbn[48+c0], s0, lbn[24+c0]);
    float t1 = fmaf(-lbn[48+c1], s1, lbn[24+c1]);
    float t2 = fmaf(-lbn[48+c2], s2, lbn[24+c2]);
    A0 = s0*LOG2E; A1 = s1*LOG2E; A2 = s2*LOG2E; Bc = (t0+t1+t2)*LOG2E;
  }
  float q[XPT][4];
  #pragma unroll
  for (int i = 0; i < XPT; ++i) {
    int x = t + i*NT;
    float4 qq = *(const float4*)(qb + (kvbase + x)*4);
    q[i][0]=qq.x; q[i][1]=qq.y; q[i][2]=qq.z; q[i][3]=qq.w;
  }
  float m2[XPT], ss[XPT], av[XPT][8], ae[XPT][8];
  #pragma unroll
  for (int i=0;i<XPT;++i){ m2[i]=-3.0e38f; ss[i]=0.f;
    #pragma unroll
    for(int d=0;d<8;++d){ av[i][d]=0.f; ae[i][d]=0.f; } }
  __syncthreads();
  for (int y = 0; y < LEN; ++y) {
    uint4 vv = sV[y];             // broadcast
    uint2 kk = sK[y];             // broadcast
    float k0=bflo(kk.x), k1=bfhi(kk.x), k2=bflo(kk.y), k3=bfhi(kk.y);
    float v0=bflo(vv.x), v1=bfhi(vv.x), v2=bflo(vv.y), v3=bfhi(vv.y);
    float v4=bflo(vv.z), v5=bfhi(vv.z), v6=bflo(vv.w), v7=bfhi(vv.w);
    #pragma unroll
    for (int i = 0; i < XPT; ++i) {
      int x = t + i*NT;
      int j = y - x + (LEN-1);    // per-lane dense, stride-16B -> conflict-free
      uint4 qe = sQK[j];
      uint4 ve = sVE[j];
      float qk = fmaf(q[i][3],k3, fmaf(q[i][2],k2, fmaf(q[i][1],k1, q[i][0]*k0)));
      float qr = fmaf(q[i][3],bfhi(qe.y), fmaf(q[i][2],bflo(qe.y),
                 fmaf(q[i][1],bfhi(qe.x), q[i][0]*bflo(qe.x))));
      float kr = fmaf(k3,bfhi(qe.w), fmaf(k2,bflo(qe.w),
                 fmaf(k1,bfhi(qe.z), k0*bflo(qe.z))));
      float l2 = fmaf(qk,A0, fmaf(qr,A1, fmaf(kr,A2, Bc)));
      float e;
      if (l2 > m2[i]) {
        float sc = __builtin_amdgcn_exp2f(m2[i] - l2);
        m2[i] = l2;
        ss[i] *= sc;
        #pragma unroll
        for (int d=0; d<8; ++d){ av[i][d]*=sc; ae[i][d]*=sc; }
        e = 1.0f;
      } else {
        e = __builtin_amdgcn_exp2f(l2 - m2[i]);
      }
      ss[i] += e;
      av[i][0]=fmaf(e,v0,av[i][0]); av[i][1]=fmaf(e,v1,av[i][1]);
      av[i][2]=fmaf(e,v2,av[i][2]); av[i][3]=fmaf(e,v3,av[i][3]);
      av[i][4]=fmaf(e,v4,av[i][4]); av[i][5]=fmaf(e,v5,av[i][5]);
      av[i][6]=fmaf(e,v6,av[i][6]); av[i][7]=fmaf(e,v7,av[i][7]);
      ae[i][0]=fmaf(e,bflo(ve.x),ae[i][0]); ae[i][1]=fmaf(e,bfhi(ve.x),ae[i][1]);
      ae[i][2]=fmaf(e,bflo(ve.y),ae[i][2]); ae[i][3]=fmaf(e,bfhi(ve.y),ae[i][3]);
      ae[i][4]=fmaf(e,bflo(ve.z),ae[i][4]); ae[i][5]=fmaf(e,bfhi(ve.z),ae[i][5]);
      ae[i][6]=fmaf(e,bflo(ve.w),ae[i][6]); ae[i][7]=fmaf(e,bfhi(ve.w),ae[i][7]);
    }
  }
  #pragma unroll
  for (int i = 0; i < XPT; ++i) {
    int x = t + i*NT;
    float inv = 1.0f / ss[i];
    float* dst = out + ((size_t)x*XS + (size_t)n*NS)*64 + hd*8;
    float4 lo, hi;
    lo.x=(av[i][0]+ae[i][0])*inv; lo.y=(av[i][1]+ae[i][1])*inv;
    lo.z=(av[i][2]+ae[i][2])*inv; lo.w=(av[i][3]+ae[i][3])*inv;
    hi.x=(av[i][4]+ae[i][4])*inv; hi.y=(av[i][5]+ae[i][5])*inv;
    hi.z=(av[i][6]+ae[i][6])*inv; hi.w=(av[i][7]+ae[i][7])*inv;
    if (RELUO) {
      lo.x=fmaxf(lo.x,0.f); lo.y=fmaxf(lo.y,0.f); lo.z=fmaxf(lo.z,0.f); lo.w=fmaxf(lo.w,0.f);
      hi.x=fmaxf(hi.x,0.f); hi.y=fmaxf(hi.y,0.f); hi.z=fmaxf(hi.z,0.f); hi.w=fmaxf(hi.w,0.f);
    }
    *(float4*)dst = lo;
    *((float4*)dst + 1) = hi;
  }
}

extern "C" void kernel_launch(void* const* d_in, const int* in_sizes, int n_in,
                              void* d_out, int out_size, void* d_ws, size_t ws_size,
                              hipStream_t stream) {
  const float* x         = (const float*)d_in[0];
  const float* conv1_w   = (const float*)d_in[1];
  const float* bn1       = (const float*)d_in[2];
  const float* kqv_w_h   = (const float*)d_in[3];
  const float* kqv_bn_h  = (const float*)d_in[4];
  const float* lbn_h     = (const float*)d_in[5];
  const float* rel_h     = (const float*)d_in[6];
  const float* kqv_w_w   = (const float*)d_in[7];
  const float* kqv_bn_w  = (const float*)d_in[8];
  const float* lbn_w     = (const float*)d_in[9];
  const float* rel_w     = (const float*)d_in[10];
  const float* conv3_w   = (const float*)d_in[11];
  const float* bn3       = (const float*)d_in[12];
  float* outp = (float*)d_out;
  char* ws = (char*)d_ws;

  // workspace layout (bytes)
  float* A    = (float*)(ws);                    // 8 MiB: y1 / OH / OW (reused)
  uint4* kvV  = (uint4*)(ws + 8388608);          // 4 MiB
  uint2* kvK  = (uint2*)(ws + 12582912);         // 2 MiB
  float* qb   = (float*)(ws + 14680064);         // 4 MiB
  uint4* rqkH = (uint4*)(ws + 18874368);         // 8176 B
  uint4* rveH = (uint4*)(ws + 18882560);         // 8176 B
  uint4* rqkW = (uint4*)(ws + 18890752);         // 4080 B
  uint4* rveW = (uint4*)(ws + 18894848);         // 4080 B

  k_relpack<<<1, 512, 0, stream>>>(rel_h, rqkH, rveH, 511);
  k_relpack<<<1, 256, 0, stream>>>(rel_w, rqkW, rveW, 255);

  // conv1 + bn1 + relu : x NCHW -> A NHWC
  k_conv<false,false><<<dim3(128,4), 256, 0, stream>>>(x, conv1_w, bn1, nullptr, A);

  // axial-H: n = w (128), seq = h (256)
  k_kqv<256,128,1><<<dim3(128,2,4), 256, 0, stream>>>(A, kqv_w_h, kqv_bn_h, kvV, kvK, qb);
  k_attn<256,2,false,128,1><<<1024, 128, 0, stream>>>(kvV, kvK, qb, rqkH, rveH, lbn_h, A);

  // axial-W: n = h (256), seq = w (128); relu fused into output
  k_kqv<128,1,128><<<dim3(256,2,2), 256, 0, stream>>>(A, kqv_w_w, kqv_bn_w, kvV, kvK, qb);
  k_attn<128,2,true,1,128><<<2048, 64, 0, stream>>>(kvV, kvK, qb, rqkW, rveW, lbn_w, A);

  // conv3 + bn3 + residual + relu : A NHWC -> out NCHW
  k_conv<true,true><<<dim3(128,4), 256, 0, stream>>>(A, conv3_w, bn3, x, outp);
}

// Round 2
// 303.812 us; speedup vs baseline: 1.1570x; 1.1570x over previous
//
#include <hip/hip_runtime.h>
#include <stdint.h>

#define EPSF 1e-5f
#define LOG2E 1.4426950408889634f

__device__ __forceinline__ float bflo(uint32_t u){ union{uint32_t u;float f;}c; c.u=u<<16; return c.f; }
__device__ __forceinline__ float bfhi(uint32_t u){ union{uint32_t u;float f;}c; c.u=u&0xffff0000u; return c.f; }
// raw high-half: value == bf16_hi * (1+delta), |delta| <= 2^-7 (low bits are the other bf16's bits)
__device__ __forceinline__ float bfhiraw(uint32_t u){ union{uint32_t u;float f;}c; c.u=u; return c.f; }
__device__ __forceinline__ uint32_t f2bf(float f){ union{float f;uint32_t u;}c; c.f=f; uint32_t u=c.u; return (u + 0x7fffu + ((u>>16)&1u)) >> 16; }
__device__ __forceinline__ uint32_t pk2(float a, float b){ return f2bf(a) | (f2bf(b)<<16); }

// ---------------- rel_enc packing ----------------
__global__ void k_relpack(const float* __restrict__ rel, uint4* __restrict__ rqk,
                          uint4* __restrict__ rve, int NJ) {
  int j = threadIdx.x;
  if (j >= NJ) return;
  const float* q = rel;
  const float* k = rel + 4*NJ;
  const float* v = rel + 8*NJ;
  int jr = NJ-1-j;
  uint4 a;
  a.x = pk2(q[0*NJ+j], q[1*NJ+j]);
  a.y = pk2(q[2*NJ+j], q[3*NJ+j]);
  a.z = pk2(k[0*NJ+jr], k[1*NJ+jr]);
  a.w = pk2(k[2*NJ+jr], k[3*NJ+jr]);
  rqk[j] = a;
  uint4 b;
  b.x = pk2(v[0*NJ+j], v[1*NJ+j]);
  b.y = pk2(v[2*NJ+j], v[3*NJ+j]);
  b.z = pk2(v[4*NJ+j], v[5*NJ+j]);
  b.w = pk2(v[6*NJ+j], v[7*NJ+j]);
  rve[j] = b;
}

// ---------------- 1x1 conv + bn (+residual/relu) ----------------
template<bool IN_NHWC, bool RESID>
__global__ __launch_bounds__(256)
void k_conv(const float* __restrict__ in, const float* __restrict__ w,
            const float* __restrict__ bn, const float* __restrict__ resid,
            float* __restrict__ out) {
  int p = blockIdx.x * 256 + threadIdx.x;
  int ob = blockIdx.y * 16;
  float xv[64];
  if (IN_NHWC) {
    const float4* src = (const float4*)(in + (size_t)p*64);
    #pragma unroll
    for (int c4 = 0; c4 < 16; ++c4) {
      float4 t = src[c4];
      xv[4*c4+0]=t.x; xv[4*c4+1]=t.y; xv[4*c4+2]=t.z; xv[4*c4+3]=t.w;
    }
  } else {
    #pragma unroll
    for (int c = 0; c < 64; ++c) xv[c] = in[c*32768 + p];
  }
  #pragma unroll
  for (int r = 0; r < 16; ++r) {
    int o = ob + r;
    const float* wr = w + o*64;
    float acc = 0.f;
    #pragma unroll
    for (int c = 0; c < 64; ++c) acc = fmaf(wr[c], xv[c], acc);
    float s = bn[o] * rsqrtf(bn[192+o] + EPSF);
    float val = fmaf(acc, s, fmaf(-bn[128+o], s, bn[64+o]));
    if (RESID) {
      val = fmaxf(val + resid[o*32768 + p], 0.f);
      out[o*32768 + p] = val;
    } else {
      out[(size_t)p*64 + o] = fmaxf(val, 0.f);
    }
  }
}

// ---------------- kqv projection + bn, packed outputs ----------------
template<int LEN, int RS, int CS>
__global__ __launch_bounds__(256)
void k_kqv(const float* __restrict__ in, const float* __restrict__ w,
           const float* __restrict__ bn, uint4* __restrict__ kvV,
           uint2* __restrict__ kvK, float* __restrict__ qb) {
  int n = blockIdx.x;
  int head = __builtin_amdgcn_readfirstlane(blockIdx.y*4 + (threadIdx.x>>6));
  int lane = threadIdx.x & 63;
  int y = blockIdx.z*64 + lane;
  const float* src = in + ((size_t)y*RS + (size_t)n*CS)*64;
  float xv[64];
  #pragma unroll
  for (int c4 = 0; c4 < 16; ++c4) {
    float4 t = ((const float4*)src)[c4];
    xv[4*c4+0]=t.x; xv[4*c4+1]=t.y; xv[4*c4+2]=t.z; xv[4*c4+3]=t.w;
  }
  float val[16];
  #pragma unroll
  for (int r = 0; r < 16; ++r) {
    int o = head*16 + r;
    const float* wr = w + o*64;
    float acc = 0.f;
    #pragma unroll
    for (int c = 0; c < 64; ++c) acc = fmaf(wr[c], xv[c], acc);
    float s = bn[o] * rsqrtf(bn[384+o] + EPSF);
    val[r] = fmaf(acc, s, fmaf(-bn[256+o], s, bn[128+o]));
  }
  size_t base = ((size_t)n*8 + head)*LEN + y;
  uint4 vv; vv.x = pk2(val[8],val[9]);  vv.y = pk2(val[10],val[11]);
            vv.z = pk2(val[12],val[13]); vv.w = pk2(val[14],val[15]);
  kvV[base] = vv;
  uint2 kk; kk.x = pk2(val[0],val[1]); kk.y = pk2(val[2],val[3]);
  kvK[base] = kk;
  float4 qq; qq.x = val[4]; qq.y = val[5]; qq.z = val[6]; qq.w = val[7];
  *(float4*)(qb + base*4) = qq;
}

// ---------------- axial attention core (v2) ----------------
// block = (n, head), threads = LEN (2 y-groups of HALF threads).
// thread (g, tl) handles x = tl, tl+HALF over y in [g*HALF, (g+1)*HALF).
// Chunked branchless online softmax (chunk=8 logits in regs).
// Partials merged in-LDS across the two y-groups.
template<int LEN, bool RELUO, int XS, int NS>
__global__ __launch_bounds__(LEN, 4)
void k_attn2(const uint4* __restrict__ kvV, const uint2* __restrict__ kvK,
             const float* __restrict__ qb, const uint4* __restrict__ rqk,
             const uint4* __restrict__ rve, const float* __restrict__ lbn,
             float* __restrict__ out) {
  constexpr int NJ = 2*LEN-1;
  constexpr int HALF = LEN/2;
  constexpr int CH = 8;
  int n  = blockIdx.x >> 3;
  int hd = blockIdx.x & 7;
  int t  = threadIdx.x;

  __shared__ __align__(16) char pool[(size_t)LEN*48 + (size_t)NJ*48];
  float4* sK   = (float4*)(pool);                 // [LEN] k0..3 f32
  float4* sVa  = (float4*)(pool + (size_t)LEN*16);// [LEN] v0..3
  float4* sVb  = (float4*)(pool + (size_t)LEN*32);// [LEN] v4..7
  uint4*  sT   = (uint4*) (pool + (size_t)LEN*48);// [NJ] qe01,qe23,ke01R,ke23R bf16pk
  float4* sVE0 = (float4*)(pool + (size_t)LEN*48 + (size_t)NJ*16); // [NJ] ve0..3 f32
  float4* sVE1 = (float4*)(pool + (size_t)LEN*48 + (size_t)NJ*32); // [NJ] ve4..7 f32

  size_t kvbase = ((size_t)n*8 + hd)*LEN;
  { // stage K/V (exact unpack, one entry per thread)
    uint2 kk = kvK[kvbase + t];
    uint4 vv = kvV[kvbase + t];
    sK[t]  = make_float4(bflo(kk.x), bfhi(kk.x), bflo(kk.y), bfhi(kk.y));
    sVa[t] = make_float4(bflo(vv.x), bfhi(vv.x), bflo(vv.y), bfhi(vv.y));
    sVb[t] = make_float4(bflo(vv.z), bfhi(vv.z), bflo(vv.w), bfhi(vv.w));
  }
  for (int j = t; j < NJ; j += LEN) {
    sT[j] = rqk[j];
    uint4 ve = rve[j];
    sVE0[j] = make_float4(bflo(ve.x), bfhi(ve.x), bflo(ve.y), bfhi(ve.y));
    sVE1[j] = make_float4(bflo(ve.z), bfhi(ve.z), bflo(ve.w), bfhi(ve.w));
  }

  // logits-bn constants (block-uniform -> scalar)
  float A0,A1,A2,Bc;
  {
    int c0 = hd, c1 = 8+hd, c2 = 16+hd;
    float s0 = lbn[c0]*rsqrtf(lbn[72+c0]+EPSF);
    float s1 = lbn[c1]*rsqrtf(lbn[72+c1]+EPSF);
    float s2 = lbn[c2]*rsqrtf(lbn[72+c2]+EPSF);
    float t0 = fmaf(-lbn[48+c0], s0, lbn[24+c0]);
    float t1 = fmaf(-lbn[48+c1], s1, lbn[24+c1]);
    float t2 = fmaf(-lbn[48+c2], s2, lbn[24+c2]);
    A0 = s0*LOG2E; A1 = s1*LOG2E; A2 = s2*LOG2E; Bc = (t0+t1+t2)*LOG2E;
  }

  int g  = t / HALF;
  int tl = t % HALF;
  int y0 = g * HALF;

  float q[2][4];
  #pragma unroll
  for (int i = 0; i < 2; ++i) {
    float4 qq = *(const float4*)(qb + (kvbase + tl + i*HALF)*4);
    q[i][0]=qq.x; q[i][1]=qq.y; q[i][2]=qq.z; q[i][3]=qq.w;
  }
  float m[2], ss[2], acc[2][8], lr[2][CH];
  #pragma unroll
  for (int i=0;i<2;++i){ m[i]=-3.0e38f; ss[i]=0.f;
    #pragma unroll
    for(int d=0;d<8;++d) acc[i][d]=0.f; }

  __syncthreads();

  for (int yc = 0; yc < HALF; yc += CH) {
    float cm0 = m[0], cm1 = m[1];
    // ---- pass A: logits ----
    #pragma unroll
    for (int c = 0; c < CH; ++c) {
      int y = y0 + yc + c;
      float4 kk = sK[y];   // broadcast
      #pragma unroll
      for (int i = 0; i < 2; ++i) {
        int j = y - (tl + i*HALF) + (LEN-1);
        uint4 qe = sT[j];
        float qk = fmaf(q[i][3],kk.w, fmaf(q[i][2],kk.z, fmaf(q[i][1],kk.y, q[i][0]*kk.x)));
        float qr = fmaf(q[i][1],bfhiraw(qe.x), q[i][0]*bflo(qe.x));
        qr = fmaf(q[i][3],bfhiraw(qe.y), fmaf(q[i][2],bflo(qe.y), qr));
        float kr = fmaf(kk.y,bfhiraw(qe.z), kk.x*bflo(qe.z));
        kr = fmaf(kk.w,bfhiraw(qe.w), fmaf(kk.z,bflo(qe.w), kr));
        float l2 = fmaf(qk,A0, fmaf(qr,A1, fmaf(kr,A2, Bc)));
        lr[i][c] = l2;
        if (i == 0) cm0 = fmaxf(cm0, l2); else cm1 = fmaxf(cm1, l2);
      }
    }
    // ---- branchless chunk rescale ----
    {
      float mn0 = fmaxf(m[0], cm0);
      float sc0 = __builtin_amdgcn_exp2f(m[0] - mn0);
      m[0] = mn0; ss[0] *= sc0;
      #pragma unroll
      for (int d = 0; d < 8; ++d) acc[0][d] *= sc0;
      float mn1 = fmaxf(m[1], cm1);
      float sc1 = __builtin_amdgcn_exp2f(m[1] - mn1);
      m[1] = mn1; ss[1] *= sc1;
      #pragma unroll
      for (int d = 0; d < 8; ++d) acc[1][d] *= sc1;
    }
    // ---- pass B: exp + accumulate ----
    #pragma unroll
    for (int c = 0; c < CH; ++c) {
      int y = y0 + yc + c;
      float4 va = sVa[y], vb = sVb[y];   // broadcast
      #pragma unroll
      for (int i = 0; i < 2; ++i) {
        int j = y - (tl + i*HALF) + (LEN-1);
        float4 ea = sVE0[j];
        float4 eb = sVE1[j];
        float e = __builtin_amdgcn_exp2f(lr[i][c] - m[i]);
        ss[i] += e;
        acc[i][0] = fmaf(e, va.x + ea.x, acc[i][0]);
        acc[i][1] = fmaf(e, va.y + ea.y, acc[i][1]);
        acc[i][2] = fmaf(e, va.z + ea.z, acc[i][2]);
        acc[i][3] = fmaf(e, va.w + ea.w, acc[i][3]);
        acc[i][4] = fmaf(e, vb.x + eb.x, acc[i][4]);
        acc[i][5] = fmaf(e, vb.y + eb.y, acc[i][5]);
        acc[i][6] = fmaf(e, vb.z + eb.z, acc[i][6]);
        acc[i][7] = fmaf(e, vb.w + eb.w, acc[i][7]);
      }
    }
  }

  // ---- merge the two y-groups via LDS ----
  __syncthreads();
  float4* M0 = (float4*)(pool);                    // [HALF*2] acc0..3
  float4* M1 = (float4*)(pool + (size_t)HALF*32);  // [HALF*2] acc4..7
  float2* MS = (float2*)(pool + (size_t)HALF*64);  // [HALF*2] (m, ss)
  if (g == 1) {
    #pragma unroll
    for (int i = 0; i < 2; ++i) {
      M0[tl*2+i] = make_float4(acc[i][0],acc[i][1],acc[i][2],acc[i][3]);
      M1[tl*2+i] = make_float4(acc[i][4],acc[i][5],acc[i][6],acc[i][7]);
      MS[tl*2+i] = make_float2(m[i], ss[i]);
    }
  }
  __syncthreads();
  if (g == 0) {
    #pragma unroll
    for (int i = 0; i < 2; ++i) {
      float2 os = MS[tl*2+i];
      float4 a0 = M0[tl*2+i];
      float4 a1 = M1[tl*2+i];
      float M  = fmaxf(m[i], os.x);
      float w0 = __builtin_amdgcn_exp2f(m[i] - M);
      float w1 = __builtin_amdgcn_exp2f(os.x - M);
      float inv = 1.0f / (ss[i]*w0 + os.y*w1);
      int x = tl + i*HALF;
      float* dst = out + ((size_t)x*XS + (size_t)n*NS)*64 + hd*8;
      float4 lo, hi;
      lo.x = (acc[i][0]*w0 + a0.x*w1)*inv;
      lo.y = (acc[i][1]*w0 + a0.y*w1)*inv;
      lo.z = (acc[i][2]*w0 + a0.z*w1)*inv;
      lo.w = (acc[i][3]*w0 + a0.w*w1)*inv;
      hi.x = (acc[i][4]*w0 + a1.x*w1)*inv;
      hi.y = (acc[i][5]*w0 + a1.y*w1)*inv;
      hi.z = (acc[i][6]*w0 + a1.z*w1)*inv;
      hi.w = (acc[i][7]*w0 + a1.w*w1)*inv;
      if (RELUO) {
        lo.x=fmaxf(lo.x,0.f); lo.y=fmaxf(lo.y,0.f); lo.z=fmaxf(lo.z,0.f); lo.w=fmaxf(lo.w,0.f);
        hi.x=fmaxf(hi.x,0.f); hi.y=fmaxf(hi.y,0.f); hi.z=fmaxf(hi.z,0.f); hi.w=fmaxf(hi.w,0.f);
      }
      *(float4*)dst = lo;
      *((float4*)dst + 1) = hi;
    }
  }
}

extern "C" void kernel_launch(void* const* d_in, const int* in_sizes, int n_in,
                              void* d_out, int out_size, void* d_ws, size_t ws_size,
                              hipStream_t stream) {
  const float* x         = (const float*)d_in[0];
  const float* conv1_w   = (const float*)d_in[1];
  const float* bn1       = (const float*)d_in[2];
  const float* kqv_w_h   = (const float*)d_in[3];
  const float* kqv_bn_h  = (const float*)d_in[4];
  const float* lbn_h     = (const float*)d_in[5];
  const float* rel_h     = (const float*)d_in[6];
  const float* kqv_w_w   = (const float*)d_in[7];
  const float* kqv_bn_w  = (const float*)d_in[8];
  const float* lbn_w     = (const float*)d_in[9];
  const float* rel_w     = (const float*)d_in[10];
  const float* conv3_w   = (const float*)d_in[11];
  const float* bn3       = (const float*)d_in[12];
  float* outp = (float*)d_out;
  char* ws = (char*)d_ws;

  float* A    = (float*)(ws);                    // 8 MiB
  uint4* kvV  = (uint4*)(ws + 8388608);          // 4 MiB
  uint2* kvK  = (uint2*)(ws + 12582912);         // 2 MiB
  float* qb   = (float*)(ws + 14680064);         // 4 MiB
  uint4* rqkH = (uint4*)(ws + 18874368);
  uint4* rveH = (uint4*)(ws + 18882560);
  uint4* rqkW = (uint4*)(ws + 18890752);
  uint4* rveW = (uint4*)(ws + 18894848);

  k_relpack<<<1, 512, 0, stream>>>(rel_h, rqkH, rveH, 511);
  k_relpack<<<1, 256, 0, stream>>>(rel_w, rqkW, rveW, 255);

  // conv1 + bn1 + relu : x NCHW -> A NHWC
  k_conv<false,false><<<dim3(128,4), 256, 0, stream>>>(x, conv1_w, bn1, nullptr, A);

  // axial-H: n = w (128), seq = h (256)
  k_kqv<256,128,1><<<dim3(128,2,4), 256, 0, stream>>>(A, kqv_w_h, kqv_bn_h, kvV, kvK, qb);
  k_attn2<256,false,128,1><<<1024, 256, 0, stream>>>(kvV, kvK, qb, rqkH, rveH, lbn_h, A);

  // axial-W: n = h (256), seq = w (128); relu fused into output
  k_kqv<128,1,128><<<dim3(256,2,2), 256, 0, stream>>>(A, kqv_w_w, kqv_bn_w, kvV, kvK, qb);
  k_attn2<128,true,1,128><<<2048, 128, 0, stream>>>(kvV, kvK, qb, rqkW, rveW, lbn_w, A);

  // conv3 + bn3 + residual + relu : A NHWC -> out NCHW
  k_conv<true,true><<<dim3(128,4), 256, 0, stream>>>(A, conv3_w, bn3, x, outp);
}

// Round 3
// 208.325 us; speedup vs baseline: 1.6874x; 1.4584x over previous
//
#include <hip/hip_runtime.h>
#include <stdint.h>

#define EPSF 1e-5f
#define LOG2E 1.4426950408889634f

__device__ __forceinline__ float bflo(uint32_t u){ union{uint32_t u;float f;}c; c.u=u<<16; return c.f; }
__device__ __forceinline__ float bfhi(uint32_t u){ union{uint32_t u;float f;}c; c.u=u&0xffff0000u; return c.f; }
// raw high-half: value == bf16_hi * (1+delta), |delta| <= 2^-7
__device__ __forceinline__ float bfhiraw(uint32_t u){ union{uint32_t u;float f;}c; c.u=u; return c.f; }
__device__ __forceinline__ uint32_t f2bf(float f){ union{float f;uint32_t u;}c; c.f=f; uint32_t u=c.u; return (u + 0x7fffu + ((u>>16)&1u)) >> 16; }
__device__ __forceinline__ uint32_t pk2(float a, float b){ return f2bf(a) | (f2bf(b)<<16); }

// ---------------- rel_enc packing ----------------
__global__ void k_relpack(const float* __restrict__ rel, uint4* __restrict__ rqk,
                          uint4* __restrict__ rve, int NJ) {
  int j = threadIdx.x;
  if (j >= NJ) return;
  const float* q = rel;
  const float* k = rel + 4*NJ;
  const float* v = rel + 8*NJ;
  int jr = NJ-1-j;
  uint4 a;
  a.x = pk2(q[0*NJ+j], q[1*NJ+j]);
  a.y = pk2(q[2*NJ+j], q[3*NJ+j]);
  a.z = pk2(k[0*NJ+jr], k[1*NJ+jr]);
  a.w = pk2(k[2*NJ+jr], k[3*NJ+jr]);
  rqk[j] = a;
  uint4 b;
  b.x = pk2(v[0*NJ+j], v[1*NJ+j]);
  b.y = pk2(v[2*NJ+j], v[3*NJ+j]);
  b.z = pk2(v[4*NJ+j], v[5*NJ+j]);
  b.w = pk2(v[6*NJ+j], v[7*NJ+j]);
  rve[j] = b;
}

// ---------------- 1x1 conv + bn (+residual/relu) ----------------
template<bool IN_NHWC, bool RESID>
__global__ __launch_bounds__(256)
void k_conv(const float* __restrict__ in, const float* __restrict__ w,
            const float* __restrict__ bn, const float* __restrict__ resid,
            float* __restrict__ out) {
  int p = blockIdx.x * 256 + threadIdx.x;
  int ob = blockIdx.y * 16;
  float xv[64];
  if (IN_NHWC) {
    const float4* src = (const float4*)(in + (size_t)p*64);
    #pragma unroll
    for (int c4 = 0; c4 < 16; ++c4) {
      float4 t = src[c4];
      xv[4*c4+0]=t.x; xv[4*c4+1]=t.y; xv[4*c4+2]=t.z; xv[4*c4+3]=t.w;
    }
  } else {
    #pragma unroll
    for (int c = 0; c < 64; ++c) xv[c] = in[c*32768 + p];
  }
  #pragma unroll
  for (int r = 0; r < 16; ++r) {
    int o = ob + r;
    const float* wr = w + o*64;
    float acc = 0.f;
    #pragma unroll
    for (int c = 0; c < 64; ++c) acc = fmaf(wr[c], xv[c], acc);
    float s = bn[o] * rsqrtf(bn[192+o] + EPSF);
    float val = fmaf(acc, s, fmaf(-bn[128+o], s, bn[64+o]));
    if (RESID) {
      val = fmaxf(val + resid[o*32768 + p], 0.f);
      out[o*32768 + p] = val;
    } else {
      out[(size_t)p*64 + o] = fmaxf(val, 0.f);
    }
  }
}

// ---------------- kqv projection + bn, packed outputs ----------------
template<int LEN, int RS, int CS>
__global__ __launch_bounds__(256)
void k_kqv(const float* __restrict__ in, const float* __restrict__ w,
           const float* __restrict__ bn, uint4* __restrict__ kvV,
           uint2* __restrict__ kvK, float* __restrict__ qb) {
  int n = blockIdx.x;
  int head = __builtin_amdgcn_readfirstlane(blockIdx.y*4 + (threadIdx.x>>6));
  int lane = threadIdx.x & 63;
  int y = blockIdx.z*64 + lane;
  const float* src = in + ((size_t)y*RS + (size_t)n*CS)*64;
  float xv[64];
  #pragma unroll
  for (int c4 = 0; c4 < 16; ++c4) {
    float4 t = ((const float4*)src)[c4];
    xv[4*c4+0]=t.x; xv[4*c4+1]=t.y; xv[4*c4+2]=t.z; xv[4*c4+3]=t.w;
  }
  float val[16];
  #pragma unroll
  for (int r = 0; r < 16; ++r) {
    int o = head*16 + r;
    const float* wr = w + o*64;
    float acc = 0.f;
    #pragma unroll
    for (int c = 0; c < 64; ++c) acc = fmaf(wr[c], xv[c], acc);
    float s = bn[o] * rsqrtf(bn[384+o] + EPSF);
    val[r] = fmaf(acc, s, fmaf(-bn[256+o], s, bn[128+o]));
  }
  size_t base = ((size_t)n*8 + head)*LEN + y;
  uint4 vv; vv.x = pk2(val[8],val[9]);  vv.y = pk2(val[10],val[11]);
            vv.z = pk2(val[12],val[13]); vv.w = pk2(val[14],val[15]);
  kvV[base] = vv;
  uint2 kk; kk.x = pk2(val[0],val[1]); kk.y = pk2(val[2],val[3]);
  kvK[base] = kk;
  float4 qq; qq.x = val[4]; qq.y = val[5]; qq.z = val[6]; qq.w = val[7];
  *(float4*)(qb + base*4) = qq;
}

// ---------------- axial attention core (v3: no-spill) ----------------
// block = (n, head), threads = LEN (2 y-groups of HALF threads).
// thread (g, tl) handles x = tl, tl+HALF over y in [g*HALF, (g+1)*HALF).
// Chunked branchless online softmax, CH=4 logits in regs.
template<int LEN, bool RELUO, int XS, int NS>
__global__ __launch_bounds__(LEN, 2)
void k_attn2(const uint4* __restrict__ kvV, const uint2* __restrict__ kvK,
             const float* __restrict__ qb, const uint4* __restrict__ rqk,
             const uint4* __restrict__ rve, const float* __restrict__ lbn,
             float* __restrict__ out) {
  constexpr int NJ = 2*LEN-1;
  constexpr int HALF = LEN/2;
  constexpr int CH = 4;
  int n  = blockIdx.x >> 3;
  int hd = blockIdx.x & 7;
  int t  = threadIdx.x;

  __shared__ __align__(16) char pool[(size_t)LEN*48 + (size_t)NJ*48];
  float4* sK   = (float4*)(pool);                 // [LEN] k0..3 f32
  float4* sVa  = (float4*)(pool + (size_t)LEN*16);// [LEN] v0..3
  float4* sVb  = (float4*)(pool + (size_t)LEN*32);// [LEN] v4..7
  uint4*  sT   = (uint4*) (pool + (size_t)LEN*48);// [NJ] qe01,qe23,ke01R,ke23R bf16pk
  float4* sVE0 = (float4*)(pool + (size_t)LEN*48 + (size_t)NJ*16); // [NJ] ve0..3 f32
  float4* sVE1 = (float4*)(pool + (size_t)LEN*48 + (size_t)NJ*32); // [NJ] ve4..7 f32

  size_t kvbase = ((size_t)n*8 + hd)*LEN;
  {
    uint2 kk = kvK[kvbase + t];
    uint4 vv = kvV[kvbase + t];
    sK[t]  = make_float4(bflo(kk.x), bfhi(kk.x), bflo(kk.y), bfhi(kk.y));
    sVa[t] = make_float4(bflo(vv.x), bfhi(vv.x), bflo(vv.y), bfhi(vv.y));
    sVb[t] = make_float4(bflo(vv.z), bfhi(vv.z), bflo(vv.w), bfhi(vv.w));
  }
  for (int j = t; j < NJ; j += LEN) {
    sT[j] = rqk[j];
    uint4 ve = rve[j];
    sVE0[j] = make_float4(bflo(ve.x), bfhi(ve.x), bflo(ve.y), bfhi(ve.y));
    sVE1[j] = make_float4(bflo(ve.z), bfhi(ve.z), bflo(ve.w), bfhi(ve.w));
  }

  float A0,A1,A2,Bc;
  {
    int c0 = hd, c1 = 8+hd, c2 = 16+hd;
    float s0 = lbn[c0]*rsqrtf(lbn[72+c0]+EPSF);
    float s1 = lbn[c1]*rsqrtf(lbn[72+c1]+EPSF);
    float s2 = lbn[c2]*rsqrtf(lbn[72+c2]+EPSF);
    float t0 = fmaf(-lbn[48+c0], s0, lbn[24+c0]);
    float t1 = fmaf(-lbn[48+c1], s1, lbn[24+c1]);
    float t2 = fmaf(-lbn[48+c2], s2, lbn[24+c2]);
    A0 = s0*LOG2E; A1 = s1*LOG2E; A2 = s2*LOG2E; Bc = (t0+t1+t2)*LOG2E;
  }

  int g  = t / HALF;
  int tl = t % HALF;
  int y0 = g * HALF;

  float q[2][4];
  #pragma unroll
  for (int i = 0; i < 2; ++i) {
    float4 qq = *(const float4*)(qb + (kvbase + tl + i*HALF)*4);
    q[i][0]=qq.x; q[i][1]=qq.y; q[i][2]=qq.z; q[i][3]=qq.w;
  }
  float m[2], ss[2], acc[2][8], lr[2][CH];
  #pragma unroll
  for (int i=0;i<2;++i){ m[i]=-3.0e38f; ss[i]=0.f;
    #pragma unroll
    for(int d=0;d<8;++d) acc[i][d]=0.f; }

  __syncthreads();

  for (int yc = 0; yc < HALF; yc += CH) {
    // ---- pass A: logits into regs ----
    #pragma unroll
    for (int c = 0; c < CH; ++c) {
      int y = y0 + yc + c;
      float4 kk = sK[y];   // broadcast
      #pragma unroll
      for (int i = 0; i < 2; ++i) {
        int j = y - (tl + i*HALF) + (LEN-1);
        uint4 qe = sT[j];
        float qk = fmaf(q[i][3],kk.w, fmaf(q[i][2],kk.z, fmaf(q[i][1],kk.y, q[i][0]*kk.x)));
        float qr = fmaf(q[i][1],bfhiraw(qe.x), q[i][0]*bflo(qe.x));
        qr = fmaf(q[i][3],bfhiraw(qe.y), fmaf(q[i][2],bflo(qe.y), qr));
        float kr = fmaf(kk.y,bfhiraw(qe.z), kk.x*bflo(qe.z));
        kr = fmaf(kk.w,bfhiraw(qe.w), fmaf(kk.z,bflo(qe.w), kr));
        lr[i][c] = fmaf(qk,A0, fmaf(qr,A1, fmaf(kr,A2, Bc)));
      }
    }
    // ---- branchless chunk rescale (chunk max via max3 trees) ----
    #pragma unroll
    for (int i = 0; i < 2; ++i) {
      float cm = fmaxf(fmaxf(lr[i][0], lr[i][1]), fmaxf(lr[i][2], lr[i][3]));
      float mn = fmaxf(m[i], cm);
      float sc = __builtin_amdgcn_exp2f(m[i] - mn);
      m[i] = mn; ss[i] *= sc;
      #pragma unroll
      for (int d = 0; d < 8; ++d) acc[i][d] *= sc;
    }
    // ---- pass B: exp + accumulate ----
    #pragma unroll
    for (int c = 0; c < CH; ++c) {
      int y = y0 + yc + c;
      float4 va = sVa[y], vb = sVb[y];   // broadcast
      #pragma unroll
      for (int i = 0; i < 2; ++i) {
        int j = y - (tl + i*HALF) + (LEN-1);
        float4 ea = sVE0[j];
        float4 eb = sVE1[j];
        float e = __builtin_amdgcn_exp2f(lr[i][c] - m[i]);
        ss[i] += e;
        acc[i][0] = fmaf(e, va.x + ea.x, acc[i][0]);
        acc[i][1] = fmaf(e, va.y + ea.y, acc[i][1]);
        acc[i][2] = fmaf(e, va.z + ea.z, acc[i][2]);
        acc[i][3] = fmaf(e, va.w + ea.w, acc[i][3]);
        acc[i][4] = fmaf(e, vb.x + eb.x, acc[i][4]);
        acc[i][5] = fmaf(e, vb.y + eb.y, acc[i][5]);
        acc[i][6] = fmaf(e, vb.z + eb.z, acc[i][6]);
        acc[i][7] = fmaf(e, vb.w + eb.w, acc[i][7]);
      }
    }
  }

  // ---- merge the two y-groups via LDS ----
  __syncthreads();
  float4* M0 = (float4*)(pool);                    // [HALF*2] acc0..3
  float4* M1 = (float4*)(pool + (size_t)HALF*32);  // [HALF*2] acc4..7
  float2* MS = (float2*)(pool + (size_t)HALF*64);  // [HALF*2] (m, ss)
  if (g == 1) {
    #pragma unroll
    for (int i = 0; i < 2; ++i) {
      M0[tl*2+i] = make_float4(acc[i][0],acc[i][1],acc[i][2],acc[i][3]);
      M1[tl*2+i] = make_float4(acc[i][4],acc[i][5],acc[i][6],acc[i][7]);
      MS[tl*2+i] = make_float2(m[i], ss[i]);
    }
  }
  __syncthreads();
  if (g == 0) {
    #pragma unroll
    for (int i = 0; i < 2; ++i) {
      float2 os = MS[tl*2+i];
      float4 a0 = M0[tl*2+i];
      float4 a1 = M1[tl*2+i];
      float M  = fmaxf(m[i], os.x);
      float w0 = __builtin_amdgcn_exp2f(m[i] - M);
      float w1 = __builtin_amdgcn_exp2f(os.x - M);
      float inv = 1.0f / (ss[i]*w0 + os.y*w1);
      int x = tl + i*HALF;
      float* dst = out + ((size_t)x*XS + (size_t)n*NS)*64 + hd*8;
      float4 lo, hi;
      lo.x = (acc[i][0]*w0 + a0.x*w1)*inv;
      lo.y = (acc[i][1]*w0 + a0.y*w1)*inv;
      lo.z = (acc[i][2]*w0 + a0.z*w1)*inv;
      lo.w = (acc[i][3]*w0 + a0.w*w1)*inv;
      hi.x = (acc[i][4]*w0 + a1.x*w1)*inv;
      hi.y = (acc[i][5]*w0 + a1.y*w1)*inv;
      hi.z = (acc[i][6]*w0 + a1.z*w1)*inv;
      hi.w = (acc[i][7]*w0 + a1.w*w1)*inv;
      if (RELUO) {
        lo.x=fmaxf(lo.x,0.f); lo.y=fmaxf(lo.y,0.f); lo.z=fmaxf(lo.z,0.f); lo.w=fmaxf(lo.w,0.f);
        hi.x=fmaxf(hi.x,0.f); hi.y=fmaxf(hi.y,0.f); hi.z=fmaxf(hi.z,0.f); hi.w=fmaxf(hi.w,0.f);
      }
      *(float4*)dst = lo;
      *((float4*)dst + 1) = hi;
    }
  }
}

extern "C" void kernel_launch(void* const* d_in, const int* in_sizes, int n_in,
                              void* d_out, int out_size, void* d_ws, size_t ws_size,
                              hipStream_t stream) {
  const float* x         = (const float*)d_in[0];
  const float* conv1_w   = (const float*)d_in[1];
  const float* bn1       = (const float*)d_in[2];
  const float* kqv_w_h   = (const float*)d_in[3];
  const float* kqv_bn_h  = (const float*)d_in[4];
  const float* lbn_h     = (const float*)d_in[5];
  const float* rel_h     = (const float*)d_in[6];
  const float* kqv_w_w   = (const float*)d_in[7];
  const float* kqv_bn_w  = (const float*)d_in[8];
  const float* lbn_w     = (const float*)d_in[9];
  const float* rel_w     = (const float*)d_in[10];
  const float* conv3_w   = (const float*)d_in[11];
  const float* bn3       = (const float*)d_in[12];
  float* outp = (float*)d_out;
  char* ws = (char*)d_ws;

  float* A    = (float*)(ws);                    // 8 MiB
  uint4* kvV  = (uint4*)(ws + 8388608);          // 4 MiB
  uint2* kvK  = (uint2*)(ws + 12582912);         // 2 MiB
  float* qb   = (float*)(ws + 14680064);         // 4 MiB
  uint4* rqkH = (uint4*)(ws + 18874368);
  uint4* rveH = (uint4*)(ws + 18882560);
  uint4* rqkW = (uint4*)(ws + 18890752);
  uint4* rveW = (uint4*)(ws + 18894848);

  k_relpack<<<1, 512, 0, stream>>>(rel_h, rqkH, rveH, 511);
  k_relpack<<<1, 256, 0, stream>>>(rel_w, rqkW, rveW, 255);

  // conv1 + bn1 + relu : x NCHW -> A NHWC
  k_conv<false,false><<<dim3(128,4), 256, 0, stream>>>(x, conv1_w, bn1, nullptr, A);

  // axial-H: n = w (128), seq = h (256)
  k_kqv<256,128,1><<<dim3(128,2,4), 256, 0, stream>>>(A, kqv_w_h, kqv_bn_h, kvV, kvK, qb);
  k_attn2<256,false,128,1><<<1024, 256, 0, stream>>>(kvV, kvK, qb, rqkH, rveH, lbn_h, A);

  // axial-W: n = h (256), seq = w (128); relu fused into output
  k_kqv<128,1,128><<<dim3(256,2,2), 256, 0, stream>>>(A, kqv_w_w, kqv_bn_w, kvV, kvK, qb);
  k_attn2<128,true,1,128><<<2048, 128, 0, stream>>>(kvV, kvK, qb, rqkW, rveW, lbn_w, A);

  // conv3 + bn3 + residual + relu : A NHWC -> out NCHW
  k_conv<true,true><<<dim3(128,4), 256, 0, stream>>>(A, conv3_w, bn3, x, outp);
}